// Round 10
// baseline (541.093 us; speedup 1.0000x reference)
//
#include <hip/hip_runtime.h>
#include <hip/hip_bf16.h>
#include <cfloat>

#define NROWS 4096
#define DDIM 1024
#define NT 64                    // 64x64 tiles per dimension
#define NBLK (NT * (NT + 1) / 2) // 2080 triangular blocks
#define NSLOT (NT + 1)           // 65 partial slots per column

typedef float f2 __attribute__((ext_vector_type(2)));
typedef float f4 __attribute__((ext_vector_type(4)));

// acc = max(acc, |x|, |y|) in one VOP3. Safe ONLY when acc is arch-VGPR:
// at launch_bounds budget 256 the 64-float acc stays in VGPRs (r2 precedent,
// VGPR_Count 92); at budget 170 it goes AGPR and "+v" forces accvgpr
// shuttles (r5 lesson, +2 instr/4elem).
#define MAX3ABS_ASM(ACC, X, Y) \
    asm("v_max3_f32 %0, abs(%1), abs(%2), %0" : "+v"(ACC) : "v"(X), "v"(Y))

// lexicographic (val, idx) merge: keep smaller val, tie -> smaller idx
#define MERGE(BV, BI, V, I) \
    do { if ((V) < (BV) || ((V) == (BV) && (I) < (BI))) { BV = (V); BI = (I); } } while (0)

// ---------------------------------------------------------------------------
// Kernel 1a: per-row max + normalize into ws (fast path). One wave per row.
// ---------------------------------------------------------------------------
__global__ __launch_bounds__(256) void normalize_kernel(const float* __restrict__ feats,
                                                        const int* __restrict__ normflag,
                                                        float* __restrict__ normf) {
    const int wave = threadIdx.x >> 6;
    const int lane = threadIdx.x & 63;
    const int row  = blockIdx.x * 4 + wave;
    const float* fr = feats + (size_t)row * DDIM;
    float*       fw = normf + (size_t)row * DDIM;
    float4 v[4];
    float m = 0.0f;  // feats uniform [0,1): nonnegative
#pragma unroll
    for (int k = 0; k < 4; ++k) {
        v[k] = *(const float4*)(fr + lane * 4 + k * 256);
        m = fmaxf(fmaxf(fmaxf(m, v[k].x), fmaxf(v[k].y, v[k].z)), v[k].w);
    }
#pragma unroll
    for (int off = 32; off > 0; off >>= 1) m = fmaxf(m, __shfl_xor(m, off));
    const float r = (*normflag != 0) ? m : 1.0f;
#pragma unroll
    for (int k = 0; k < 4; ++k) {
        v[k].x /= r; v[k].y /= r; v[k].z /= r; v[k].w /= r;
        *(float4*)(fw + lane * 4 + k * 256) = v[k];
    }
}

// Kernel 1b (fallback when ws is small): per-row max only.
__global__ __launch_bounds__(256) void rowmax_kernel(const float* __restrict__ feats,
                                                     const int* __restrict__ normflag,
                                                     float* __restrict__ rowmax) {
    const int wave = threadIdx.x >> 6;
    const int lane = threadIdx.x & 63;
    const int row  = blockIdx.x * 4 + wave;
    const float* fr = feats + (size_t)row * DDIM;
    float m = 0.0f;
    for (int d = lane * 4; d < DDIM; d += 256) {
        float4 v = *(const float4*)(fr + d);
        m = fmaxf(fmaxf(fmaxf(m, v.x), fmaxf(v.y, v.z)), v.w);
    }
#pragma unroll
    for (int off = 32; off > 0; off >>= 1) m = fmaxf(m, __shfl_xor(m, off));
    if (lane == 0) rowmax[row] = (*normflag != 0) ? m : 1.0f;
}

// ---------------------------------------------------------------------------
// Kernel 2: 128 threads (2 waves) per triangular 64x64 tile block. Both
// waves hold full 8x8-per-lane accumulators over the same tile, split by q
// (wave w does q in {4w..4w+3}). launch_bounds(128,2): VGPR budget 256
// (~155 used, all arch-VGPR -> asm max3 shuttle-free, no spills) and
// 4 resident blocks/CU — r3 proved >=3 dephased blocks saturate the shared
// LDS pipe while other blocks' waves run VALU (r6/r8's 2 lockstep blocks
// serialized the pipes; r9's double-buffer spilled to scratch, 672 MB HBM
// writes). Single-buffer staging + register prefetch (r6 proven).
// Inner body: f2 subs (v_pk_add_f32 candidate) + asm v_max3(abs,abs,acc):
// 4-6 VALU per 4 elems. Swizzle q^(row&7): A-reads 8 distinct rows per
// 16-lane group -> conflict-free; B-reads broadcast; writes 2-way (free).
// ---------------------------------------------------------------------------
template <bool NORM>
__global__ __launch_bounds__(128, 2) void cheb_kernel(const float* __restrict__ src,
                                                      const float* __restrict__ rowmax,
                                                      const int* __restrict__ labels,
                                                      float* __restrict__ pval,
                                                      int* __restrict__ pidx) {
    // XCD-bijective swizzle (NBLK % 8 == 0), then triangular decode.
    int bid = blockIdx.x;
    bid = (bid & 7) * (NBLK / 8) + (bid >> 3);
    float fs = sqrtf((float)((2 * NT + 1) * (2 * NT + 1) - 8 * bid));
    int ta = (int)(((float)(2 * NT + 1) - fs) * 0.5f);
    while ((ta + 1) * NT - ((ta + 1) * ta) / 2 <= bid) ++ta;      // start(ta+1) <= bid
    while (ta * NT - (ta * (ta - 1)) / 2 > bid) --ta;             // start(ta)  >  bid
    const int tb = ta + (bid - (ta * NT - (ta * (ta - 1)) / 2));
    const int iBase = ta * 64;
    const int jBase = tb * 64;

    const int t    = threadIdx.x;
    const int w    = t >> 6;          // wave 0..1 (q-slice owner)
    const int lane = t & 63;
    const int ty8  = lane & 7;        // row group
    const int tx8  = lane >> 3;       // col group

    __shared__ __align__(16) float lds[4096];   // 16 KB: As | Bs, reused as merge buf
    float* As = lds;
    float* Bs = lds + 2048;

    float acc[8][8];
#pragma unroll
    for (int kk = 0; kk < 8; ++kk)
#pragma unroll
        for (int jj = 0; jj < 8; ++jj) acc[kk][jj] = 0.0f;

    // Staging: thread handles rows r0+16k (k=0..3), chunk q0, for A and B.
    // (r0+16k)&7 == r0&7, so the swizzled offset is shared across k.
    const int r0  = t >> 3;           // 0..15
    const int q0  = t & 7;
    const int swz = 4 * (q0 ^ (r0 & 7));
    int oS[4];
    const float* gA[4];
    const float* gB[4];
    float rmA[4], rmB[4];
#pragma unroll
    for (int k = 0; k < 4; ++k) {
        const int r = r0 + 16 * k;
        oS[k] = r * 32 + swz;
        gA[k] = src + (size_t)(iBase + r) * DDIM + 4 * q0;
        gB[k] = src + (size_t)(jBase + r) * DDIM + 4 * q0;
        if (NORM) { rmA[k] = rowmax[iBase + r]; rmB[k] = rowmax[jBase + r]; }
    }

    const char* Ab = (const char*)As + ty8 * 128;
    const char* Bb = (const char*)Bs + tx8 * 128;

    // Register prefetch of chunk 0.
    float4 pa[4], pb[4];
#pragma unroll
    for (int k = 0; k < 4; ++k) {
        pa[k] = *(const float4*)(gA[k]);
        pb[k] = *(const float4*)(gB[k]);
    }

#pragma unroll 1
    for (int dc = 0; dc < DDIM / 32; ++dc) {
        __syncthreads();                 // previous chunk's reads complete
#pragma unroll
        for (int k = 0; k < 4; ++k) {
            if (NORM) {
                pa[k].x /= rmA[k]; pa[k].y /= rmA[k]; pa[k].z /= rmA[k]; pa[k].w /= rmA[k];
                pb[k].x /= rmB[k]; pb[k].y /= rmB[k]; pb[k].z /= rmB[k]; pb[k].w /= rmB[k];
            }
            *(float4*)(As + oS[k]) = pa[k];
            *(float4*)(Bs + oS[k]) = pb[k];
        }
        __syncthreads();

        if (dc + 1 < DDIM / 32) {        // prefetch next chunk; hides under compute
            const int dB = (dc + 1) * 32;
#pragma unroll
            for (int k = 0; k < 4; ++k) {
                pa[k] = *(const float4*)(gA[k] + dB);
                pb[k] = *(const float4*)(gB[k] + dB);
            }
        }

#pragma unroll
        for (int qi = 0; qi < 4; ++qi) {
            const int q  = 4 * w + qi;
            const int oa = 16 * (q ^ ty8);
            const int ob = 16 * (q ^ tx8);
            f2 blo[8], bhi[8];
#pragma unroll
            for (int jj = 0; jj < 8; ++jj) {
                const f4 b = *(const f4*)(Bb + jj * 1024 + ob);
                blo[jj] = __builtin_shufflevector(b, b, 0, 1);
                bhi[jj] = __builtin_shufflevector(b, b, 2, 3);
            }
#pragma unroll
            for (int kk = 0; kk < 8; ++kk) {
                const f4 a = *(const f4*)(Ab + kk * 1024 + oa);
                const f2 alo = __builtin_shufflevector(a, a, 0, 1);
                const f2 ahi = __builtin_shufflevector(a, a, 2, 3);
#pragma unroll
                for (int jj = 0; jj < 8; ++jj) {
                    const f2 dlo = alo - blo[jj];    // v_pk_add_f32 candidate
                    const f2 dhi = ahi - bhi[jj];
                    MAX3ABS_ASM(acc[kk][jj], dlo[0], dlo[1]);
                    MAX3ABS_ASM(acc[kk][jj], dhi[0], dhi[1]);
                }
            }
        }
    }

    // Labels (only wave 0 needs them) issued early to hide latency under merge.
    int lA[8], lB[8];
    if (w == 0) {
#pragma unroll
        for (int kk = 0; kk < 8; ++kk) lA[kk] = labels[iBase + ty8 + 8 * kk];
#pragma unroll
        for (int jj = 0; jj < 8; ++jj) lB[jj] = labels[jBase + tx8 + 8 * jj];
    }

    // ---- Max-merge wave 1's q-partial accumulator into wave 0. ----
    // mbuf layout: lane L, float4-group g at float index L*64 + 4*(g^(L&15)):
    // 16-lane group reads/writes 8 distinct quads, 2 lanes each (free).
    float* mbuf = lds;                   // As/Bs are dead now
    __syncthreads();
    if (w == 1) {
#pragma unroll
        for (int g = 0; g < 16; ++g) {
            float4 v;
            v.x = acc[g >> 1][(g & 1) * 4 + 0]; v.y = acc[g >> 1][(g & 1) * 4 + 1];
            v.z = acc[g >> 1][(g & 1) * 4 + 2]; v.w = acc[g >> 1][(g & 1) * 4 + 3];
            *(float4*)(mbuf + lane * 64 + 4 * (g ^ (lane & 15))) = v;
        }
    }
    __syncthreads();
    if (w == 0) {
#pragma unroll
        for (int g = 0; g < 16; ++g) {
            float4 v = *(const float4*)(mbuf + lane * 64 + 4 * (g ^ (lane & 15)));
            acc[g >> 1][(g & 1) * 4 + 0] = fmaxf(acc[g >> 1][(g & 1) * 4 + 0], v.x);
            acc[g >> 1][(g & 1) * 4 + 1] = fmaxf(acc[g >> 1][(g & 1) * 4 + 1], v.y);
            acc[g >> 1][(g & 1) * 4 + 2] = fmaxf(acc[g >> 1][(g & 1) * 4 + 2], v.z);
            acc[g >> 1][(g & 1) * 4 + 3] = fmaxf(acc[g >> 1][(g & 1) * 4 + 3], v.w);
        }

        // ---- Orientation 1: per column (tb-tile), min over this block's rows.
#pragma unroll
        for (int jj = 0; jj < 8; ++jj) {
            float bv = FLT_MAX; int bi = 0x7fffffff;
#pragma unroll
            for (int kk = 0; kk < 8; ++kk) {
                const int i = iBase + ty8 + 8 * kk;
                const float v = (lA[kk] == lB[jj]) ? FLT_MAX : acc[kk][jj];
                MERGE(bv, bi, v, i);
            }
#pragma unroll
            for (int off = 1; off <= 4; off <<= 1) {     // reduce over ty8
                const float ov = __shfl_xor(bv, off);
                const int   oi = __shfl_xor(bi, off);
                MERGE(bv, bi, ov, oi);
            }
            if (ty8 == 0) {
                const int j = jBase + tx8 + 8 * jj;
                pval[ta * NROWS + j] = bv;
                pidx[ta * NROWS + j] = bi;
            }
        }
        // ---- Orientation 2: per row (ta-tile), min over this block's cols.
#pragma unroll
        for (int kk = 0; kk < 8; ++kk) {
            float bv = FLT_MAX; int bi = 0x7fffffff;
#pragma unroll
            for (int jj = 0; jj < 8; ++jj) {
                const int j = jBase + tx8 + 8 * jj;
                const float v = (lA[kk] == lB[jj]) ? FLT_MAX : acc[kk][jj];
                MERGE(bv, bi, v, j);
            }
#pragma unroll
            for (int off = 8; off <= 32; off <<= 1) {    // reduce over tx8
                const float ov = __shfl_xor(bv, off);
                const int   oi = __shfl_xor(bi, off);
                MERGE(bv, bi, ov, oi);
            }
            if (tx8 == 0) {
                const int i = iBase + ty8 + 8 * kk;
                pval[(tb + 1) * NROWS + i] = bv;
                pidx[(tb + 1) * NROWS + i] = bi;
            }
        }
    }
}

// ---------------------------------------------------------------------------
// Kernel 3a: combine 65 partial slots per column; write indices + colmin.
// ---------------------------------------------------------------------------
__global__ __launch_bounds__(256) void finalizeA_kernel(const float* __restrict__ pval,
                                                        const int* __restrict__ pidx,
                                                        const int* __restrict__ image_idxs,
                                                        float* __restrict__ out,
                                                        float* __restrict__ colmin) {
    const int j = blockIdx.x * 256 + threadIdx.x;
    float bv = FLT_MAX; int bi = 0x7fffffff;
    for (int s = 0; s < NSLOT; ++s) {
        const float v = pval[s * NROWS + j];
        const int   i = pidx[s * NROWS + j];
        MERGE(bv, bi, v, i);
    }
    out[1 + j] = (float)image_idxs[bi];
    colmin[j] = bv;
}

// Kernel 3b: deterministic sum of colmin -> loss.
__global__ __launch_bounds__(256) void finalizeB_kernel(const float* __restrict__ colmin,
                                                        float* __restrict__ out) {
    const int t = threadIdx.x;
    float s = 0.0f;
#pragma unroll
    for (int k = 0; k < 16; ++k) s += colmin[t + 256 * k];
#pragma unroll
    for (int off = 32; off > 0; off >>= 1) s += __shfl_xor(s, off);
    __shared__ float ss[4];
    if ((t & 63) == 0) ss[t >> 6] = s;
    __syncthreads();
    if (t == 0) out[0] = (ss[0] + ss[1] + ss[2] + ss[3]) / (float)NROWS;
}

// ---------------------------------------------------------------------------
extern "C" void kernel_launch(void* const* d_in, const int* in_sizes, int n_in,
                              void* d_out, int out_size, void* d_ws, size_t ws_size,
                              hipStream_t stream) {
    const float* feats      = (const float*)d_in[0];
    const int*   labels     = (const int*)d_in[1];
    const int*   image_idxs = (const int*)d_in[2];
    const int*   normflag   = (const int*)d_in[3];
    float*       out        = (float*)d_out;

    const size_t normBytes = (size_t)NROWS * DDIM * sizeof(float);          // 16 MB
    const size_t partBytes = (size_t)NSLOT * NROWS * 8 + NROWS * 4;         // ~2.15 MB

    if (ws_size >= normBytes + partBytes) {
        float* normf  = (float*)d_ws;
        float* pval   = (float*)((char*)d_ws + normBytes);
        int*   pidx   = (int*)(pval + NSLOT * NROWS);
        float* colmin = (float*)(pidx + NSLOT * NROWS);
        normalize_kernel<<<NROWS / 4, 256, 0, stream>>>(feats, normflag, normf);
        cheb_kernel<false><<<NBLK, 128, 0, stream>>>(normf, nullptr, labels, pval, pidx);
        finalizeA_kernel<<<NROWS / 256, 256, 0, stream>>>(pval, pidx, image_idxs, out, colmin);
        finalizeB_kernel<<<1, 256, 0, stream>>>(colmin, out);
    } else {
        float* rowmax = (float*)d_ws;
        float* pval   = rowmax + NROWS;
        int*   pidx   = (int*)(pval + NSLOT * NROWS);
        float* colmin = (float*)(pidx + NSLOT * NROWS);
        rowmax_kernel<<<NROWS / 4, 256, 0, stream>>>(feats, normflag, rowmax);
        cheb_kernel<true><<<NBLK, 128, 0, stream>>>(feats, rowmax, labels, pval, pidx);
        finalizeA_kernel<<<NROWS / 256, 256, 0, stream>>>(pval, pidx, image_idxs, out, colmin);
        finalizeB_kernel<<<1, 256, 0, stream>>>(colmin, out);
    }
}